// Round 2
// baseline (16969.501 us; speedup 1.0000x reference)
//
#include <hip/hip_runtime.h>
#include <hip/hip_bf16.h>
#include <stdint.h>

// Problem constants
#define N_B     64
#define T_STEPS 1024
#define T1      1025
#define VOCAB   10000
#define DIM     512
#define HID     512
#define FOURH   2048
#define GBLK    64      // workgroups in persistent scan kernel (8 hid dims each)

typedef unsigned short u16;
typedef unsigned int   u32;
typedef short bf16x8 __attribute__((ext_vector_type(8)));   // 8 bf16 = 4 VGPRs
typedef float f32x16 __attribute__((ext_vector_type(16)));  // 32x32 MFMA acc

__device__ __forceinline__ float bf2f(u16 x){
  union { u32 u; float f; } v; v.u = ((u32)x) << 16; return v.f;
}
__device__ __forceinline__ u16 f2bf(float f){
  union { float f; u32 u; } v; v.f = f;
  u32 u = v.u;
  return (u16)((u + 0x7FFFu + ((u >> 16) & 1u)) >> 16);  // RNE
}
__device__ __forceinline__ bf16x8 ldfrag(const u16* p){
  union { uint4 q; bf16x8 s; } v; v.q = *(const uint4*)p; return v.s;
}
__device__ __forceinline__ float fsig(float x){
  return 1.0f / (1.0f + exp2f(x * -1.44269504f));
}
__device__ __forceinline__ float ftanh(float x){
  return 1.0f - 2.0f / (1.0f + exp2f(x * 2.88539008f));  // saturates at +/-1
}

// ---- transpose+convert Wx, Wh (512 x 2048 fp32) -> bf16 (2048 x 512) ----
__global__ void k_transpose(const float* __restrict__ Wx, const float* __restrict__ Wh,
                            u16* __restrict__ WxT, u16* __restrict__ WhT){
  int b = blockIdx.x;
  const float* src = Wx; u16* dst = WxT;
  if (b >= 512){ src = Wh; dst = WhT; b -= 512; }
  int id = b * 256 + threadIdx.x;       // 131072 ids: 2048 cols x 64 k-chunks
  int n  = id & (FOURH - 1);            // source col (consecutive per lane -> coalesced)
  int kc = (id >> 11) << 3;             // k chunk of 8
  u32 w[4];
  #pragma unroll
  for (int j = 0; j < 4; j++){
    u32 lo = (u32)f2bf(src[(kc + 2*j    ) * FOURH + n]);
    u32 hi = (u32)f2bf(src[(kc + 2*j + 1) * FOURH + n]);
    w[j] = lo | (hi << 16);
  }
  uint4 q; q.x = w[0]; q.y = w[1]; q.z = w[2]; q.w = w[3];
  *(uint4*)(dst + n * DIM + kc) = q;
}

// ---- convert W_embed (10000 x 512 fp32) -> bf16, same layout ----
__global__ void k_wemb(const float* __restrict__ Wemb, u16* __restrict__ We16){
  int i = blockIdx.x * 256 + threadIdx.x;        // 2,560,000 ids, 2 elems each
  float2 f = *(const float2*)(Wemb + 2 * i);
  u32 pk = (u32)f2bf(f.x) | ((u32)f2bf(f.y) << 16);
  *(u32*)(We16 + 2 * i) = pk;
}

// ---- init h buffers (hi/lo split of fp32 h0) + barrier counter ----
__global__ void k_init(const float* __restrict__ h0, u16* __restrict__ h_hi,
                       u16* __restrict__ h_lo, u32* cnt){
  int i = blockIdx.x * 256 + threadIdx.x;   // 32768
  float f = h0[i];
  u16 hb = f2bf(f);
  h_hi[i] = hb;
  h_lo[i] = f2bf(f - bf2f(hb));
  if (i == 0) *cnt = 0;
}

// ---- E = W_embed @ Wx + b  (10000 x 2048, bf16) ----
__launch_bounds__(256)
__global__ void k_egemm(const u16* __restrict__ Wemb, const u16* __restrict__ WxT,
                        const float* __restrict__ bias, u16* __restrict__ E){
  int nb = blockIdx.x;            // 0..15  -> cols nb*128
  int mb = blockIdx.y;            // 0..78  -> rows mb*128
  int wv   = threadIdx.x >> 6;
  int lane = threadIdx.x & 63;
  int l31 = lane & 31, hi5 = lane >> 5;
  int mrow = mb * 128 + wv * 32 + l31;
  int mcl  = mrow < VOCAB ? mrow : VOCAB - 1;
  const u16* ap  = Wemb + (u32)mcl * DIM + hi5 * 8;
  const u16* bp0 = WxT + (u32)(nb * 128 +  0 + l31) * DIM + hi5 * 8;
  const u16* bp1 = bp0 + 32 * DIM;
  const u16* bp2 = bp0 + 64 * DIM;
  const u16* bp3 = bp0 + 96 * DIM;
  f32x16 acc[4] = {};
  for (int ks = 0; ks < 32; ks++){
    bf16x8 av = ldfrag(ap);  ap  += 16;
    bf16x8 b0 = ldfrag(bp0); bp0 += 16;
    bf16x8 b1 = ldfrag(bp1); bp1 += 16;
    bf16x8 b2 = ldfrag(bp2); bp2 += 16;
    bf16x8 b3 = ldfrag(bp3); bp3 += 16;
    acc[0] = __builtin_amdgcn_mfma_f32_32x32x16_bf16(av, b0, acc[0], 0, 0, 0);
    acc[1] = __builtin_amdgcn_mfma_f32_32x32x16_bf16(av, b1, acc[1], 0, 0, 0);
    acc[2] = __builtin_amdgcn_mfma_f32_32x32x16_bf16(av, b2, acc[2], 0, 0, 0);
    acc[3] = __builtin_amdgcn_mfma_f32_32x32x16_bf16(av, b3, acc[3], 0, 0, 0);
  }
  int rbase = mb * 128 + wv * 32 + 4 * hi5;
  #pragma unroll
  for (int nt = 0; nt < 4; nt++){
    int col = nb * 128 + nt * 32 + l31;
    float bv = bias[col];
    #pragma unroll
    for (int r = 0; r < 16; r++){
      int row = rbase + (r & 3) + 8 * (r >> 2);
      if (row < VOCAB) E[(u32)row * FOURH + col] = f2bf(acc[nt][r] + bv);
    }
  }
}

// ---- persistent LSTM scan ----
// 64 blocks x 128 threads. Block g owns hidden dims [g*8, g*8+8).
// GEMM computed transposed: D = WhSlice^T(32 x K) . h^T(K x 32n) so that
// gate = reg&3 lands in the register dim -> all 4 gates in-lane.
__launch_bounds__(128, 1)
__global__ void k_scan(const int* __restrict__ cap, const u16* __restrict__ E,
                       const u16* __restrict__ WhT, u16* __restrict__ h_hi,
                       u16* __restrict__ h_lo, u32* cnt, float* __restrict__ out){
  const int g    = blockIdx.x;
  const int tid  = threadIdx.x;
  const int wv   = tid >> 6;
  const int lane = tid & 63;
  const int l31  = lane & 31, hi5 = lane >> 5;
  const int n    = wv * 32 + l31;                       // batch row (B-operand col)
  // A-operand row r_loc = l31 -> global Wh column:
  const int gc   = (l31 & 3) * HID + g * 8 + (l31 >> 2);
  const u16* wbase = WhT + (u32)gc * DIM + hi5 * 8;

  float c0 = 0.f, c1 = 0.f, c2 = 0.f, c3 = 0.f;

  // prefetch E row for t=0
  int capv = cap[n * T1];
  const u16* eb = E + (u32)capv * FOURH + g * 8;
  uint4 e0 = *(const uint4*)(eb + 0 * HID);
  uint4 e1 = *(const uint4*)(eb + 1 * HID);
  uint4 e2 = *(const uint4*)(eb + 2 * HID);
  uint4 e3 = *(const uint4*)(eb + 3 * HID);

  for (int t = 0; t < T_STEPS; t++){
    if (t > 0){
      if (tid == 0){
        u32 target = (u32)(GBLK * t);
        while (__hip_atomic_load(cnt, __ATOMIC_ACQUIRE, __HIP_MEMORY_SCOPE_AGENT) < target){}
      }
      __syncthreads();
    }
    // acc init from prefetched E (xW + b contribution)
    u32 ew[16];
    *(uint4*)&ew[0]  = e0; *(uint4*)&ew[4]  = e1;
    *(uint4*)&ew[8]  = e2; *(uint4*)&ew[12] = e3;
    f32x16 acc;
    #pragma unroll
    for (int reg = 0; reg < 16; reg++){
      int gate = reg & 3, q = reg >> 2;
      u32 d = ew[gate * 4 + q];
      acc[reg] = bf2f(hi5 ? (u16)(d >> 16) : (u16)(d & 0xFFFFu));
    }
    f32x16 acc2 = {};
    // K-loop: a += Wh^T-slice . h  (h = hi + lo bf16 pair, fp32 accumulate)
    // Two independent accumulator chains (hi stream / lo stream) for latency.
    const u16* hp = h_hi + (t & 1) * (N_B * HID) + n * HID + hi5 * 8;
    const u16* lp = h_lo + (t & 1) * (N_B * HID) + n * HID + hi5 * 8;
    const u16* wp = wbase;
    #pragma unroll 4
    for (int ks = 0; ks < 32; ks++){
      bf16x8 a  = ldfrag(wp); wp += 16;
      bf16x8 bh = ldfrag(hp); hp += 16;
      bf16x8 bl = ldfrag(lp); lp += 16;
      acc  = __builtin_amdgcn_mfma_f32_32x32x16_bf16(a, bh, acc,  0, 0, 0);
      acc2 = __builtin_amdgcn_mfma_f32_32x32x16_bf16(a, bl, acc2, 0, 0, 0);
    }
    acc += acc2;
    // prefetch next step's E while we do gate math (E/captions are static)
    capv = cap[n * T1 + t + 1];   // t+1 <= 1024 < T1, always in-bounds
    const u16* eb2 = E + (u32)capv * FOURH + g * 8;
    e0 = *(const uint4*)(eb2 + 0 * HID);
    e1 = *(const uint4*)(eb2 + 1 * HID);
    e2 = *(const uint4*)(eb2 + 2 * HID);
    e3 = *(const uint4*)(eb2 + 3 * HID);

    // LSTM cell: lane holds gates for (n, hd = g*8 + 2q + hi5), q = 0..3
    u16* hw = h_hi + ((t + 1) & 1) * (N_B * HID);
    u16* lw = h_lo + ((t + 1) & 1) * (N_B * HID);
    const int hbase = n * HID + g * 8;
    const int obase = n * (T_STEPS * HID) + t * HID + g * 8;
    #pragma unroll
    for (int q = 0; q < 4; q++){
      float ai = acc[q * 4 + 0], af = acc[q * 4 + 1];
      float ao = acc[q * 4 + 2], ag = acc[q * 4 + 3];
      float ig = fsig(ai), fg = fsig(af), og = fsig(ao), gg = ftanh(ag);
      float cc = (q == 0 ? c0 : q == 1 ? c1 : q == 2 ? c2 : c3);
      cc = fg * cc + ig * gg;
      if (q == 0) c0 = cc; else if (q == 1) c1 = cc; else if (q == 2) c2 = cc; else c3 = cc;
      float h = og * ftanh(cc);
      // fp32 output store (one float per lane per q)
      out[obase + 2 * q + hi5] = h;
      // bf16 hi/lo carry for the recurrence
      u32 hb = f2bf(h);
      float rem = h - bf2f((u16)hb);
      u32 lb = f2bf(rem);
      u32 ph = (u32)__shfl_xor((int)hb, 32);
      u32 pl = (u32)__shfl_xor((int)lb, 32);
      if (hi5 == 0){
        *(u32*)(hw + hbase + 2 * q) = hb | (ph << 16);
        *(u32*)(lw + hbase + 2 * q) = lb | (pl << 16);
      }
    }
    __threadfence();           // device-scope release of h stores
    __syncthreads();
    if (tid == 0)
      __hip_atomic_fetch_add(cnt, 1u, __ATOMIC_RELEASE, __HIP_MEMORY_SCOPE_AGENT);
  }
}

extern "C" void kernel_launch(void* const* d_in, const int* in_sizes, int n_in,
                              void* d_out, int out_size, void* d_ws, size_t ws_size,
                              hipStream_t stream){
  const int*   cap  = (const int*)d_in[0];
  const float* h0   = (const float*)d_in[1];
  const float* Wemb = (const float*)d_in[2];
  const float* Wx   = (const float*)d_in[3];
  const float* Wh   = (const float*)d_in[4];
  const float* bias = (const float*)d_in[5];
  float* out = (float*)d_out;

  char* ws = (char*)d_ws;
  const size_t OFF_E    = 0;
  const size_t OFF_WXT  = OFF_E    + (size_t)VOCAB * FOURH * 2;   // 40,960,000
  const size_t OFF_WHT  = OFF_WXT  + (size_t)FOURH * DIM * 2;     // +2 MiB
  const size_t OFF_WE16 = OFF_WHT  + (size_t)FOURH * DIM * 2;     // +2 MiB
  const size_t OFF_HHI  = OFF_WE16 + (size_t)VOCAB * DIM * 2;     // +10.24 MB
  const size_t OFF_HLO  = OFF_HHI  + (size_t)2 * N_B * HID * 2;   // +128 KiB
  const size_t OFF_CNT  = OFF_HLO  + (size_t)2 * N_B * HID * 2;   // +128 KiB

  u16* E    = (u16*)(ws + OFF_E);
  u16* WxT  = (u16*)(ws + OFF_WXT);
  u16* WhT  = (u16*)(ws + OFF_WHT);
  u16* We16 = (u16*)(ws + OFF_WE16);
  u16* h_hi = (u16*)(ws + OFF_HHI);
  u16* h_lo = (u16*)(ws + OFF_HLO);
  u32* cnt  = (u32*)(ws + OFF_CNT);

  hipLaunchKernelGGL(k_transpose, dim3(1024),   dim3(256), 0, stream, Wx, Wh, WxT, WhT);
  hipLaunchKernelGGL(k_wemb,      dim3(10000),  dim3(256), 0, stream, Wemb, We16);
  hipLaunchKernelGGL(k_init,      dim3(128),    dim3(256), 0, stream, h0, h_hi, h_lo, cnt);
  hipLaunchKernelGGL(k_egemm,     dim3(16, 79), dim3(256), 0, stream, We16, WxT, bias, E);
  hipLaunchKernelGGL(k_scan,      dim3(GBLK),   dim3(128), 0, stream, cap, E, WhT, h_hi, h_lo, cnt, out);
}

// Round 3
// 11648.759 us; speedup vs baseline: 1.4568x; 1.4568x over previous
//
#include <hip/hip_runtime.h>
#include <hip/hip_bf16.h>
#include <stdint.h>

// Problem constants
#define N_B     64
#define T_STEPS 1024
#define T1      1025
#define VOCAB   10000
#define DIM     512
#define HID     512
#define FOURH   2048
#define GBLK    64      // workgroups in persistent scan kernel (8 hid dims each)
#define FLGSTR  32      // u32 stride between block flags (128 B, own L2 line)

typedef unsigned short u16;
typedef unsigned int   u32;
typedef short bf16x8 __attribute__((ext_vector_type(8)));   // 8 bf16 = 4 VGPRs
typedef float f32x16 __attribute__((ext_vector_type(16)));  // 32x32 MFMA acc

__device__ __forceinline__ float bf2f(u16 x){
  union { u32 u; float f; } v; v.u = ((u32)x) << 16; return v.f;
}
__device__ __forceinline__ u16 f2bf(float f){
  union { float f; u32 u; } v; v.f = f;
  u32 u = v.u;
  return (u16)((u + 0x7FFFu + ((u >> 16) & 1u)) >> 16);  // RNE
}
__device__ __forceinline__ bf16x8 ldfrag(const u16* p){
  union { uint4 q; bf16x8 s; } v; v.q = *(const uint4*)p; return v.s;
}
__device__ __forceinline__ float fsig(float x){
  return 1.0f / (1.0f + exp2f(x * -1.44269504f));
}
__device__ __forceinline__ float ftanh(float x){
  return 1.0f - 2.0f / (1.0f + exp2f(x * 2.88539008f));  // saturates at +/-1
}

// ---- transpose+convert Wx, Wh (512 x 2048 fp32) -> bf16 (2048 x 512) ----
__global__ void k_transpose(const float* __restrict__ Wx, const float* __restrict__ Wh,
                            u16* __restrict__ WxT, u16* __restrict__ WhT){
  int b = blockIdx.x;
  const float* src = Wx; u16* dst = WxT;
  if (b >= 512){ src = Wh; dst = WhT; b -= 512; }
  int id = b * 256 + threadIdx.x;       // 131072 ids: 2048 cols x 64 k-chunks
  int n  = id & (FOURH - 1);            // source col (consecutive per lane -> coalesced)
  int kc = (id >> 11) << 3;             // k chunk of 8
  u32 w[4];
  #pragma unroll
  for (int j = 0; j < 4; j++){
    u32 lo = (u32)f2bf(src[(kc + 2*j    ) * FOURH + n]);
    u32 hi = (u32)f2bf(src[(kc + 2*j + 1) * FOURH + n]);
    w[j] = lo | (hi << 16);
  }
  uint4 q; q.x = w[0]; q.y = w[1]; q.z = w[2]; q.w = w[3];
  *(uint4*)(dst + n * DIM + kc) = q;
}

// ---- convert W_embed (10000 x 512 fp32) -> bf16, same layout ----
__global__ void k_wemb(const float* __restrict__ Wemb, u16* __restrict__ We16){
  int i = blockIdx.x * 256 + threadIdx.x;        // 2,560,000 ids, 2 elems each
  float2 f = *(const float2*)(Wemb + 2 * i);
  u32 pk = (u32)f2bf(f.x) | ((u32)f2bf(f.y) << 16);
  *(u32*)(We16 + 2 * i) = pk;
}

// ---- init h buffers (hi/lo split of fp32 h0) + barrier flags ----
__global__ void k_init(const float* __restrict__ h0, u16* __restrict__ h_hi,
                       u16* __restrict__ h_lo, u32* flags){
  int i = blockIdx.x * 256 + threadIdx.x;   // 32768
  float f = h0[i];
  u16 hb = f2bf(f);
  h_hi[i] = hb;
  h_lo[i] = f2bf(f - bf2f(hb));
  if (i < GBLK * FLGSTR) flags[i] = 0;
}

// ---- E = W_embed @ Wx + b  (10000 x 2048, bf16) ----
__launch_bounds__(256)
__global__ void k_egemm(const u16* __restrict__ Wemb, const u16* __restrict__ WxT,
                        const float* __restrict__ bias, u16* __restrict__ E){
  int nb = blockIdx.x;            // 0..15  -> cols nb*128
  int mb = blockIdx.y;            // 0..78  -> rows mb*128
  int wv   = threadIdx.x >> 6;
  int lane = threadIdx.x & 63;
  int l31 = lane & 31, hi5 = lane >> 5;
  int mrow = mb * 128 + wv * 32 + l31;
  int mcl  = mrow < VOCAB ? mrow : VOCAB - 1;
  const u16* ap  = Wemb + (u32)mcl * DIM + hi5 * 8;
  const u16* bp0 = WxT + (u32)(nb * 128 +  0 + l31) * DIM + hi5 * 8;
  const u16* bp1 = bp0 + 32 * DIM;
  const u16* bp2 = bp0 + 64 * DIM;
  const u16* bp3 = bp0 + 96 * DIM;
  f32x16 acc[4] = {};
  for (int ks = 0; ks < 32; ks++){
    bf16x8 av = ldfrag(ap);  ap  += 16;
    bf16x8 b0 = ldfrag(bp0); bp0 += 16;
    bf16x8 b1 = ldfrag(bp1); bp1 += 16;
    bf16x8 b2 = ldfrag(bp2); bp2 += 16;
    bf16x8 b3 = ldfrag(bp3); bp3 += 16;
    acc[0] = __builtin_amdgcn_mfma_f32_32x32x16_bf16(av, b0, acc[0], 0, 0, 0);
    acc[1] = __builtin_amdgcn_mfma_f32_32x32x16_bf16(av, b1, acc[1], 0, 0, 0);
    acc[2] = __builtin_amdgcn_mfma_f32_32x32x16_bf16(av, b2, acc[2], 0, 0, 0);
    acc[3] = __builtin_amdgcn_mfma_f32_32x32x16_bf16(av, b3, acc[3], 0, 0, 0);
  }
  int rbase = mb * 128 + wv * 32 + 4 * hi5;
  #pragma unroll
  for (int nt = 0; nt < 4; nt++){
    int col = nb * 128 + nt * 32 + l31;
    float bv = bias[col];
    #pragma unroll
    for (int r = 0; r < 16; r++){
      int row = rbase + (r & 3) + 8 * (r >> 2);
      if (row < VOCAB) E[(u32)row * FOURH + col] = f2bf(acc[nt][r] + bv);
    }
  }
}

// ---- persistent LSTM scan ----
// 64 blocks x 128 threads. Block g owns hidden dims [g*8, g*8+8).
// GEMM computed transposed: D = WhSlice^T(32 x K) . h^T(K x 32n) so that
// gate = reg&3 lands in the register dim -> all 4 gates in-lane.
// Grid barrier: distributed per-block flags (own 128B line each), wave0
// polls all 64 with one relaxed 64-lane gather; single acquire fence on exit.
__launch_bounds__(128, 1)
__global__ void k_scan(const int* __restrict__ cap, const u16* __restrict__ E,
                       const u16* __restrict__ WhT, u16* __restrict__ h_hi,
                       u16* __restrict__ h_lo, u32* flags, float* __restrict__ out){
  const int g    = blockIdx.x;
  const int tid  = threadIdx.x;
  const int wv   = tid >> 6;
  const int lane = tid & 63;
  const int l31  = lane & 31, hi5 = lane >> 5;
  const int n    = wv * 32 + l31;                       // batch row (B-operand col)
  // A-operand row r_loc = l31 -> global Wh column:
  const int gc   = (l31 & 3) * HID + g * 8 + (l31 >> 2);
  const u16* wbase = WhT + (u32)gc * DIM + hi5 * 8;

  // Wh slice is static across all 1024 steps: hold it in registers (128 VGPRs).
  bf16x8 wreg[32];
  #pragma unroll
  for (int ks = 0; ks < 32; ks++) wreg[ks] = ldfrag(wbase + 16 * ks);

  float c0 = 0.f, c1 = 0.f, c2 = 0.f, c3 = 0.f;

  // prefetch E row for t=0
  int capv = cap[n * T1];
  const u16* eb = E + (u32)capv * FOURH + g * 8;
  uint4 e0 = *(const uint4*)(eb + 0 * HID);
  uint4 e1 = *(const uint4*)(eb + 1 * HID);
  uint4 e2 = *(const uint4*)(eb + 2 * HID);
  uint4 e3 = *(const uint4*)(eb + 3 * HID);

  for (int t = 0; t < T_STEPS; t++){
    if (t > 0){
      if (tid < 64){
        u32 v;
        do {
          v = __hip_atomic_load(&flags[tid * FLGSTR], __ATOMIC_RELAXED,
                                __HIP_MEMORY_SCOPE_AGENT);
        } while (__ballot(v < (u32)t));
        // one L1/L2 invalidate per step (covers this CU's waves + this XCD)
        __builtin_amdgcn_fence(__ATOMIC_ACQUIRE, "agent");
      }
      __syncthreads();
    }
    // acc init from prefetched E (xW + b contribution)
    u32 ew[16];
    *(uint4*)&ew[0]  = e0; *(uint4*)&ew[4]  = e1;
    *(uint4*)&ew[8]  = e2; *(uint4*)&ew[12] = e3;
    f32x16 acc;
    #pragma unroll
    for (int reg = 0; reg < 16; reg++){
      int gate = reg & 3, q = reg >> 2;
      u32 d = ew[gate * 4 + q];
      acc[reg] = bf2f(hi5 ? (u16)(d >> 16) : (u16)(d & 0xFFFFu));
    }
    f32x16 acc2 = {};
    // K-loop: a += Wh^T-slice . h  (h = hi + lo bf16 pair, fp32 accumulate)
    const u16* hp = h_hi + (t & 1) * (N_B * HID) + n * HID + hi5 * 8;
    const u16* lp = h_lo + (t & 1) * (N_B * HID) + n * HID + hi5 * 8;
    #pragma unroll
    for (int ks = 0; ks < 32; ks++){
      bf16x8 bh = ldfrag(hp); hp += 16;
      bf16x8 bl = ldfrag(lp); lp += 16;
      acc  = __builtin_amdgcn_mfma_f32_32x32x16_bf16(wreg[ks], bh, acc,  0, 0, 0);
      acc2 = __builtin_amdgcn_mfma_f32_32x32x16_bf16(wreg[ks], bl, acc2, 0, 0, 0);
    }
    acc += acc2;
    // prefetch next step's E while we do gate math (E/captions are static)
    capv = cap[n * T1 + t + 1];   // t+1 <= 1024 < T1, always in-bounds
    const u16* eb2 = E + (u32)capv * FOURH + g * 8;
    e0 = *(const uint4*)(eb2 + 0 * HID);
    e1 = *(const uint4*)(eb2 + 1 * HID);
    e2 = *(const uint4*)(eb2 + 2 * HID);
    e3 = *(const uint4*)(eb2 + 3 * HID);

    // LSTM cell: lane holds gates for (n, hd = g*8 + 2q + hi5), q = 0..3
    u16* hw = h_hi + ((t + 1) & 1) * (N_B * HID);
    u16* lw = h_lo + ((t + 1) & 1) * (N_B * HID);
    const int hbase = n * HID + g * 8;
    const int obase = n * (T_STEPS * HID) + t * HID + g * 8;
    #pragma unroll
    for (int q = 0; q < 4; q++){
      float ai = acc[q * 4 + 0], af = acc[q * 4 + 1];
      float ao = acc[q * 4 + 2], ag = acc[q * 4 + 3];
      float ig = fsig(ai), fg = fsig(af), og = fsig(ao), gg = ftanh(ag);
      float cc = (q == 0 ? c0 : q == 1 ? c1 : q == 2 ? c2 : c3);
      cc = fg * cc + ig * gg;
      if (q == 0) c0 = cc; else if (q == 1) c1 = cc; else if (q == 2) c2 = cc; else c3 = cc;
      float h = og * ftanh(cc);
      // fp32 output store, write-only stream -> nontemporal
      __builtin_nontemporal_store(h, &out[obase + 2 * q + hi5]);
      // bf16 hi/lo carry for the recurrence
      u32 hb = f2bf(h);
      float rem = h - bf2f((u16)hb);
      u32 lb = f2bf(rem);
      u32 ph = (u32)__shfl_xor((int)hb, 32);
      u32 pl = (u32)__shfl_xor((int)lb, 32);
      if (hi5 == 0){
        *(u32*)(hw + hbase + 2 * q) = hb | (ph << 16);
        *(u32*)(lw + hbase + 2 * q) = lb | (pl << 16);
      }
    }
    __syncthreads();            // all h stores of this block complete (vmcnt drained)
    if (tid == 0){
      // release store: writes back this XCD's dirty L2 lines (incl. other waves'
      // h stores), then publishes "finished step t" on this block's own line.
      __hip_atomic_store(&flags[g * FLGSTR], (u32)(t + 1), __ATOMIC_RELEASE,
                         __HIP_MEMORY_SCOPE_AGENT);
    }
  }
}

extern "C" void kernel_launch(void* const* d_in, const int* in_sizes, int n_in,
                              void* d_out, int out_size, void* d_ws, size_t ws_size,
                              hipStream_t stream){
  const int*   cap  = (const int*)d_in[0];
  const float* h0   = (const float*)d_in[1];
  const float* Wemb = (const float*)d_in[2];
  const float* Wx   = (const float*)d_in[3];
  const float* Wh   = (const float*)d_in[4];
  const float* bias = (const float*)d_in[5];
  float* out = (float*)d_out;

  char* ws = (char*)d_ws;
  const size_t OFF_E    = 0;
  const size_t OFF_WXT  = OFF_E    + (size_t)VOCAB * FOURH * 2;   // 40,960,000
  const size_t OFF_WHT  = OFF_WXT  + (size_t)FOURH * DIM * 2;     // +2 MiB
  const size_t OFF_WE16 = OFF_WHT  + (size_t)FOURH * DIM * 2;     // +2 MiB
  const size_t OFF_HHI  = OFF_WE16 + (size_t)VOCAB * DIM * 2;     // +10.24 MB
  const size_t OFF_HLO  = OFF_HHI  + (size_t)2 * N_B * HID * 2;   // +128 KiB
  const size_t OFF_FLG  = OFF_HLO  + (size_t)2 * N_B * HID * 2;   // +128 KiB

  u16* E    = (u16*)(ws + OFF_E);
  u16* WxT  = (u16*)(ws + OFF_WXT);
  u16* WhT  = (u16*)(ws + OFF_WHT);
  u16* We16 = (u16*)(ws + OFF_WE16);
  u16* h_hi = (u16*)(ws + OFF_HHI);
  u16* h_lo = (u16*)(ws + OFF_HLO);
  u32* flg  = (u32*)(ws + OFF_FLG);

  hipLaunchKernelGGL(k_transpose, dim3(1024),   dim3(256), 0, stream, Wx, Wh, WxT, WhT);
  hipLaunchKernelGGL(k_wemb,      dim3(10000),  dim3(256), 0, stream, Wemb, We16);
  hipLaunchKernelGGL(k_init,      dim3(128),    dim3(256), 0, stream, h0, h_hi, h_lo, flg);
  hipLaunchKernelGGL(k_egemm,     dim3(16, 79), dim3(256), 0, stream, We16, WxT, bias, E);
  hipLaunchKernelGGL(k_scan,      dim3(GBLK),   dim3(128), 0, stream, cap, E, WhT, h_hi, h_lo, flg, out);
}